// Round 3
// baseline (548.081 us; speedup 1.0000x reference)
//
#include <hip/hip_runtime.h>
#include <math.h>

// downprompt: fused elementwise + 7-way cosine-sim + softmax.
// v4: force the memory pipeline to materialize (v3 failed: VGPR=36 proves
// the compiler collapsed the prefetch to ~2 loads in flight).
//  - __launch_bounds__(256, 4): register budget 128, so a deep pipeline fits
//  - depth-8 double-buffered register prefetch (16 loads / 16KB per wave
//    in flight at steady state)
//  - sched_barrier(0) pins: loads issue early, cannot be sunk to their uses
// Structure otherwise = v2/v3: 4 lanes/row x 16 rows/wave, coef+ave in LDS
// (broadcast ds_read_b128, conflict-free), 2-round quad reduction.

__device__ __forceinline__ float elu1(float x) {
    return x > 0.0f ? x : __expf(x) - 1.0f;
}

__device__ __forceinline__ float wave_sum(float v) {
#pragma unroll
    for (int off = 32; off > 0; off >>= 1)
        v += __shfl_xor(v, off, 64);
    return v;
}

__global__ __launch_bounds__(256, 4) void downprompt_kernel(
    const float* __restrict__ seq,
    const float* __restrict__ seq1,
    const float* __restrict__ prompt,
    const float* __restrict__ w_np,
    const float* __restrict__ w_ds,
    const float* __restrict__ w_df,
    const float* __restrict__ ave,
    float* __restrict__ out,
    int N)
{
    __shared__ float s_coef[256];
    __shared__ float s_ave[7][256];

    const int tid  = threadIdx.x;
    const int lane = tid & 63;

    // ---- block setup: stage coef[d] and ave into LDS ----
    {
        const float a  = w_df[0];
        const float b  = w_df[1];
        const float w0 = w_np[0], w1 = w_np[1], w2 = w_np[2];
        const float pr = w0 * prompt[tid] + w1 * prompt[256 + tid]
                       + w2 * prompt[512 + tid];
        s_coef[tid] = a * (1.0f + elu1(pr)) + b * w_ds[tid];
#pragma unroll
        for (int c = 0; c < 7; ++c)
            s_ave[c][tid] = ave[c * 256 + tid];
    }
    __syncthreads();

    // ---- per-wave: prototype norms (once per wave) ----
    float na[7];
#pragma unroll
    for (int c = 0; c < 7; ++c) {
        const float4 v = *(const float4*)&s_ave[c][lane << 2];
        na[c] = sqrtf(wave_sum(v.x * v.x + v.y * v.y + v.z * v.z + v.w * v.w));
    }

    // ---- 4 lanes per row, 16 rows per wave ----
    const int q   = lane & 3;    // column phase (0..3)
    const int sub = lane >> 2;   // row within group (0..15)
    const int wavesPerBlock = blockDim.x >> 6;
    const int gwave = blockIdx.x * wavesPerBlock + (tid >> 6);
    const int nwave = gridDim.x * wavesPerBlock;
    const int ngroups = (N + 15) >> 4;

    for (int g = gwave; g < ngroups; g += nwave) {
        const int row = (g << 4) + sub;
        if (row >= N) continue;   // quad-uniform: shuffles stay safe

        const float* ps = seq  + (size_t)row * 256 + (q << 2);
        const float* pt = seq1 + (size_t)row * 256 + (q << 2);

        // depth-8 double-buffered prefetch: slots 0..7 hold chunks i..i+7
        float4 sb[8], tb[8];
#pragma unroll
        for (int i = 0; i < 8; ++i) {
            sb[i] = *(const float4*)(ps + (i << 4));
            tb[i] = *(const float4*)(pt + (i << 4));
        }
        __builtin_amdgcn_sched_barrier(0);   // loads stay issued up here

        float acc[8];
#pragma unroll
        for (int k = 0; k < 8; ++k) acc[k] = 0.0f;

#pragma unroll
        for (int i = 0; i < 16; ++i) {
            const float4 s = sb[i & 7];      // consume (waitcnt lands here)
            const float4 t = tb[i & 7];
            if (i < 8) {                      // refill same slot with chunk i+8
                sb[i] = *(const float4*)(ps + ((i + 8) << 4));
                tb[i] = *(const float4*)(pt + ((i + 8) << 4));
            }
            __builtin_amdgcn_sched_barrier(0);  // prefetch cannot sink below

            const int col = (i << 4) + (q << 2);
            const float4 cf = *(const float4*)&s_coef[col];

            const float r0 = elu1(cf.x * s.x) + 0.1f * t.x;
            const float r1 = elu1(cf.y * s.y) + 0.1f * t.y;
            const float r2 = elu1(cf.z * s.z) + 0.1f * t.z;
            const float r3 = elu1(cf.w * s.w) + 0.1f * t.w;

            acc[7] += r0 * r0 + r1 * r1 + r2 * r2 + r3 * r3;
#pragma unroll
            for (int c = 0; c < 7; ++c) {
                const float4 av = *(const float4*)&s_ave[c][col];
                acc[c] += r0 * av.x + r1 * av.y + r2 * av.z + r3 * av.w;
            }
        }

        // reduce the 8 partials across the 4 lanes of this row's group
#pragma unroll
        for (int off = 1; off <= 2; off <<= 1) {
#pragma unroll
            for (int k = 0; k < 8; ++k)
                acc[k] += __shfl_xor(acc[k], off, 64);
        }

        // softmax over cosine sims (redundant x4 within the group)
        const float nr = sqrtf(acc[7]);
        float sims[7];
        float m = -INFINITY;
#pragma unroll
        for (int c = 0; c < 7; ++c) {
            const float den = fmaxf(nr * na[c], 1e-8f);
            sims[c] = acc[c] * __builtin_amdgcn_rcpf(den);
            m = fmaxf(m, sims[c]);
        }
        float e[7], sum = 0.0f;
#pragma unroll
        for (int c = 0; c < 7; ++c) {
            e[c] = __expf(sims[c] - m);
            sum += e[c];
        }
        const float inv = __builtin_amdgcn_rcpf(sum);

        // lane q writes c=q, and c=q+4 for q<3 (static indices only)
        const float eq  = (q == 0) ? e[0] : (q == 1) ? e[1]
                        : (q == 2) ? e[2] : e[3];
        const float eq4 = (q == 0) ? e[4] : (q == 1) ? e[5] : e[6];

        float* po = out + (size_t)row * 7;
        po[q] = eq * inv;
        if (q < 3) po[q + 4] = eq4 * inv;
    }
}

extern "C" void kernel_launch(void* const* d_in, const int* in_sizes, int n_in,
                              void* d_out, int out_size, void* d_ws, size_t ws_size,
                              hipStream_t stream) {
    const float* seq    = (const float*)d_in[0];
    const float* seq1   = (const float*)d_in[1];
    const float* prompt = (const float*)d_in[2];
    const float* w_np   = (const float*)d_in[3];
    const float* w_ds   = (const float*)d_in[4];
    const float* w_df   = (const float*)d_in[5];
    const float* ave    = (const float*)d_in[6];
    float* out = (float*)d_out;

    const int N = in_sizes[0] / 256;          // 200000
    const int ngroups = (N + 15) / 16;        // 12500 row-groups of 16
    const int wavesPerBlock = 4;
    // one 16-row group per wave: 3125 blocks = 12500 waves.
    // At ~4 waves/SIMD residency (VGPR ~110) that's ~3 block generations.
    int blocks = (ngroups + wavesPerBlock - 1) / wavesPerBlock;
    if (blocks < 1) blocks = 1;

    downprompt_kernel<<<blocks, 256, 0, stream>>>(seq, seq1, prompt, w_np, w_ds,
                                                  w_df, ave, out, N);
}

// Round 6
// 415.244 us; speedup vs baseline: 1.3199x; 1.3199x over previous
//
#include <hip/hip_runtime.h>
#include <math.h>

// downprompt: fused elementwise + 7-way cosine-sim + softmax.
// v7 = v6 + WAR-race fix. v6's bug: in each iteration the refill DMA
// (global_load_lds) targeted the SAME ring slot the ds_read had just been
// issued against; DS-pipe reads and DMA LDS-writes are not mutually
// ordered, so a hot DMA return could overwrite the slot before the queued
// ds_read sampled it (absmax 7.8e-3). Fix: s_waitcnt lgkmcnt(0) between
// the slot reads and the refill issue — read provably completes first.
//   - per-wave private 3-pair x 2KB LDS ring; prologue 6 DMAs in flight,
//     each iter: vmcnt(4) (counted, never 0 mid-loop) -> ds_read pair ->
//     lgkmcnt(0) -> reissue slot for chunk J+3 -> compute
//   - DMA dest = wave-uniform base + lane*16 = exactly the 16B each lane
//     consumes -> identity read-back, conflict-free stride-16 ds_read
// Structure: 4 lanes/row x 16 rows/wave, coef+ave in LDS (broadcast reads),
// 2-round quad reduction, x4-redundant softmax epilogue.

typedef __attribute__((address_space(1))) const float gbl_float;
typedef __attribute__((address_space(3))) float lds_float;

// async copy of 16B/lane into LDS slot (dest: base + lane*16)
#define ASYNC16(gp, lp) \
    __builtin_amdgcn_global_load_lds((gbl_float*)(gp), (lds_float*)(lp), 16, 0, 0)

#define VMW(N) asm volatile("s_waitcnt vmcnt(" #N ")" ::: "memory")
#define LGKW   asm volatile("s_waitcnt lgkmcnt(0)" ::: "memory")

__device__ __forceinline__ float elu1(float x) {
    return x > 0.0f ? x : __expf(x) - 1.0f;
}

__device__ __forceinline__ float wave_sum(float v) {
#pragma unroll
    for (int off = 32; off > 0; off >>= 1)
        v += __shfl_xor(v, off, 64);
    return v;
}

__global__ __launch_bounds__(256) void downprompt_kernel(
    const float* __restrict__ seq,
    const float* __restrict__ seq1,
    const float* __restrict__ prompt,
    const float* __restrict__ w_np,
    const float* __restrict__ w_ds,
    const float* __restrict__ w_df,
    const float* __restrict__ ave,
    float* __restrict__ out,
    int N)
{
    __shared__ float s_coef[256];
    __shared__ float s_ave[7][256];
    __shared__ float s_ring[4][1536];   // per-wave ring: 3 pairs x (s,t) x 256 floats

    const int tid  = threadIdx.x;
    const int lane = tid & 63;
    const int w    = tid >> 6;

    // ---- block setup: stage coef[d] and ave into LDS ----
    {
        const float a  = w_df[0];
        const float b  = w_df[1];
        const float w0 = w_np[0], w1 = w_np[1], w2 = w_np[2];
        const float pr = w0 * prompt[tid] + w1 * prompt[256 + tid]
                       + w2 * prompt[512 + tid];
        s_coef[tid] = a * (1.0f + elu1(pr)) + b * w_ds[tid];
#pragma unroll
        for (int c = 0; c < 7; ++c)
            s_ave[c][tid] = ave[c * 256 + tid];
    }
    __syncthreads();

    // ---- per-wave: prototype norms (once per wave) ----
    float na[7];
#pragma unroll
    for (int c = 0; c < 7; ++c) {
        const float4 v = *(const float4*)&s_ave[c][lane << 2];
        na[c] = sqrtf(wave_sum(v.x * v.x + v.y * v.y + v.z * v.z + v.w * v.w));
    }

    // ---- 4 lanes per row, 16 rows per wave ----
    const int q   = lane & 3;    // column phase (0..3)
    const int q4  = q << 2;
    const int l4  = lane << 2;   // this lane's float offset within a 1KB slot
    const int sub = lane >> 2;   // row within group (0..15)
    const int wavesPerBlock = blockDim.x >> 6;
    const int gwave = blockIdx.x * wavesPerBlock + (tid >> 6);
    const int nwave = gridDim.x * wavesPerBlock;
    const int ngroups = (N + 15) >> 4;

    float* const ring = &s_ring[w][0];

    for (int g = gwave; g < ngroups; g += nwave) {
        const int row = (g << 4) + sub;
        if (row >= N) continue;   // group-uniform (N%16==0 in practice)

        const float* ps = seq  + (size_t)row * 256 + q4;
        const float* pt = seq1 + (size_t)row * 256 + q4;

        // prologue: chunks 0..2 -> slot pairs 0..2 (6 DMAs in flight)
        ASYNC16(ps +  0, ring +    0);
        ASYNC16(pt +  0, ring +  256);
        ASYNC16(ps + 16, ring +  512);
        ASYNC16(pt + 16, ring +  768);
        ASYNC16(ps + 32, ring + 1024);
        ASYNC16(pt + 32, ring + 1280);

        float acc[8];
#pragma unroll
        for (int k = 0; k < 8; ++k) acc[k] = 0.0f;

        // iteration J: wait chunk J ready, consume, fence, refill slot with
        // chunk J+3. vmcnt math: at wait of iter J (J<=13) issued = 6+2J
        // loads, need 2(J+1) oldest done -> vmcnt(4); J=14 -> 2; J=15 -> 0.
        // Prior group's 2 out-stores only make the wait more conservative.
#define ITER(J, WN) do {                                                  \
        VMW(WN);                                                          \
        const float4 s = *(const float4*)(ring + ((J) % 3) * 512 + l4);   \
        const float4 t = *(const float4*)(ring + ((J) % 3) * 512 + 256 + l4); \
        LGKW;  /* slot read complete before DMA may overwrite it */       \
        if ((J) <= 12) {                                                  \
            ASYNC16(ps + ((J) + 3) * 16, ring + ((J) % 3) * 512);         \
            ASYNC16(pt + ((J) + 3) * 16, ring + ((J) % 3) * 512 + 256);   \
        }                                                                 \
        const int col = ((J) << 4) + q4;                                  \
        const float4 cf = *(const float4*)&s_coef[col];                   \
        const float r0 = elu1(cf.x * s.x) + 0.1f * t.x;                   \
        const float r1 = elu1(cf.y * s.y) + 0.1f * t.y;                   \
        const float r2 = elu1(cf.z * s.z) + 0.1f * t.z;                   \
        const float r3 = elu1(cf.w * s.w) + 0.1f * t.w;                   \
        acc[7] += r0 * r0 + r1 * r1 + r2 * r2 + r3 * r3;                  \
        _Pragma("unroll")                                                 \
        for (int c = 0; c < 7; ++c) {                                     \
            const float4 av = *(const float4*)&s_ave[c][col];             \
            acc[c] += r0 * av.x + r1 * av.y + r2 * av.z + r3 * av.w;      \
        }                                                                 \
    } while (0)

        ITER( 0, 4); ITER( 1, 4); ITER( 2, 4); ITER( 3, 4);
        ITER( 4, 4); ITER( 5, 4); ITER( 6, 4); ITER( 7, 4);
        ITER( 8, 4); ITER( 9, 4); ITER(10, 4); ITER(11, 4);
        ITER(12, 4); ITER(13, 4); ITER(14, 2); ITER(15, 0);
#undef ITER

        // reduce the 8 partials across the 4 lanes of this row's group
#pragma unroll
        for (int off = 1; off <= 2; off <<= 1) {
#pragma unroll
            for (int k = 0; k < 8; ++k)
                acc[k] += __shfl_xor(acc[k], off, 64);
        }

        // softmax over cosine sims (redundant x4 within the group)
        const float nr = sqrtf(acc[7]);
        float sims[7];
        float m = -INFINITY;
#pragma unroll
        for (int c = 0; c < 7; ++c) {
            const float den = fmaxf(nr * na[c], 1e-8f);
            sims[c] = acc[c] * __builtin_amdgcn_rcpf(den);
            m = fmaxf(m, sims[c]);
        }
        float e[7], sum = 0.0f;
#pragma unroll
        for (int c = 0; c < 7; ++c) {
            e[c] = __expf(sims[c] - m);
            sum += e[c];
        }
        const float inv = __builtin_amdgcn_rcpf(sum);

        // lane q writes c=q, and c=q+4 for q<3 (static indices only)
        const float eq  = (q == 0) ? e[0] : (q == 1) ? e[1]
                        : (q == 2) ? e[2] : e[3];
        const float eq4 = (q == 0) ? e[4] : (q == 1) ? e[5] : e[6];

        float* po = out + (size_t)row * 7;
        po[q] = eq * inv;
        if (q < 3) po[q + 4] = eq4 * inv;
    }
}

extern "C" void kernel_launch(void* const* d_in, const int* in_sizes, int n_in,
                              void* d_out, int out_size, void* d_ws, size_t ws_size,
                              hipStream_t stream) {
    const float* seq    = (const float*)d_in[0];
    const float* seq1   = (const float*)d_in[1];
    const float* prompt = (const float*)d_in[2];
    const float* w_np   = (const float*)d_in[3];
    const float* w_ds   = (const float*)d_in[4];
    const float* w_df   = (const float*)d_in[5];
    const float* ave    = (const float*)d_in[6];
    float* out = (float*)d_out;

    const int N = in_sizes[0] / 256;          // 200000
    const int ngroups = (N + 15) / 16;        // 12500 row-groups of 16
    const int wavesPerBlock = 4;
    // one 16-row group per wave: 3125 blocks = 12500 waves.
    // LDS 32KB/block -> 5 blocks/CU = 20 waves/CU resident.
    int blocks = (ngroups + wavesPerBlock - 1) / wavesPerBlock;
    if (blocks < 1) blocks = 1;

    downprompt_kernel<<<blocks, 256, 0, stream>>>(seq, seq1, prompt, w_np, w_ds,
                                                  w_df, ave, out, N);
}